// Round 9
// baseline (43267.896 us; speedup 1.0000x reference)
//
#include <hip/hip_runtime.h>
#include <cstdint>
#include <cstddef>

// NeuralODE RK4, persistent kernel. Round-9 (= round-6 seqlock design,
// resubmitted verbatim; GPU never acquired rounds 6-8):
// barrier-free wave-to-wave dataflow with SEQLOCK-TAGGED values — payload
// f32 and sequence tag share one 8-byte atom, so publish/consume needs NO
// ordering, NO fences, NO flags.
// (Round-5 failed: vmcnt(0) does not order two stores' LLC arrival; the flag
//  could land before the data. Tagged atoms make that race impossible.)
//
// Global wave gw (of 512) owns neurons 4gw..4gw+3. Tag array layout (u64):
//   Rtag[b][v][j][w] : b=buffer(2) v=vector(2) j=elem-in-chunk(4) w=wave(512)
// At phase p: consumers read buffer p&1 expecting tag p+1; at end of phase p
// owner lane r writes buffer (p+1)&1, tag p+2, planes j=r, both vectors.
// Back-pressure: publishing seq p+2 requires having observed all seq p+1,
// which (data-dependence, transitively) proves all readers of the slot being
// overwritten are done. 2 buffers suffice; tag==tgt is exact.
//
// Phase A: {u1,u2} = W @ {R_n, R_a} -> derive R_b, R_c   (publish)
// Phase B: {u3,u4} = W @ {R_b, R_c} -> y_{n+1}, R_{n+1}, R_a'  (publish)
// (identical FMA/add order to round 3 -> same trajectory, absmax 0.25)
//
// d_in: t[2048], state[4][2048], stim[2048], W[2048][2048]  (all f32)
// d_out: traj[2048][4][2048] f32
// d_ws: Rtag[2][2][4][512] u64 = 64KB (zeroed each launch by memsetAsync)

#define NWG   128
#define TPB   256
#define WPG   (TPB / 64)        // 4 waves per WG
#define NWAVE (NWG * WPG)       // 512 producer waves
#define NN    2048
#define TT    2048
#define NP    ((TT - 1) * 2)    // 4094 phases

typedef float f4 __attribute__((ext_vector_type(4)));
typedef unsigned long long u64;

__device__ __forceinline__ float dot4(const f4 a, const f4 b) {
    return a.x * b.x + a.y * b.y + a.z * b.z + a.w * b.w;
}

__device__ __forceinline__ u64 pack_tag(float v, unsigned seq) {
    return (u64)__float_as_uint(v) | ((u64)seq << 32);
}

__device__ __forceinline__ u64 tag_load(u64* p) {
    return __hip_atomic_load(p, __ATOMIC_RELAXED, __HIP_MEMORY_SCOPE_AGENT);
}

__device__ __forceinline__ void tag_store(u64* p, u64 v) {
    __hip_atomic_store(p, v, __ATOMIC_RELAXED, __HIP_MEMORY_SCOPE_AGENT);
}

__global__ __launch_bounds__(TPB, 1)
void node_rk4_kernel(const float* __restrict__ tgrid,
                     const float* __restrict__ state0,
                     const float* __restrict__ stim,
                     const float* __restrict__ W,
                     float* __restrict__ out,
                     u64* __restrict__ Rtag)
{
    const int g    = blockIdx.x;
    const int tid  = threadIdx.x;
    const int wave = tid >> 6;
    const int lane = tid & 63;
    const int gw   = g * WPG + wave;   // global wave id, 0..511
    const int myrow = 4 * gw;          // first of this wave's 4 neurons

    extern __shared__ float lds[];
    float* tg = lds;                   // TT floats (8KB)

    for (int i = tid; i < TT; i += TPB) tg[i] = tgrid[i];

    // ---- W rows into registers/AGPRs: rows myrow..+3, float4-col lane+64k ----
    f4 w[4][8];
    {
        const f4* Wg = reinterpret_cast<const f4*>(W) + (size_t)myrow * (NN / 4);
#pragma unroll
        for (int r = 0; r < 4; ++r)
#pragma unroll
            for (int k = 0; k < 8; ++k)
                w[r][k] = Wg[(size_t)r * (NN / 4) + lane + 64 * k];
    }
    __syncthreads();   // tg ready (the ONLY barrier in the kernel)

    // ---- owner state: lane r (<4) owns neuron myrow+r ----
    float yI = 0.f, yH = 0.f, yA = 0.f, yR = 0.f, st = 0.f;
    float k1I = 0.f, k1H = 0.f, k1A = 0.f, k1R = 0.f;
    float k2I = 0.f, k2H = 0.f, k2A = 0.f, k2R = 0.f;
    float bI = 0.f, bH = 0.f, bA = 0.f, bR = 0.f;

    if (lane < 4) {
        const int i = myrow + lane;
        yI = state0[0 * NN + i];
        yH = state0[1 * NN + i];
        yA = state0[2 * NN + i];
        yR = state0[3 * NN + i];
        st = stim[i];
        // publish buffer 0, tag 1: vec0 = R_n, vec1 = R_a
        const float dt0 = tg[1] - tg[0];
        const float Ra  = yR + (0.5f * dt0) * tanhf(yH - yA);
        tag_store(Rtag + (size_t)(0 * 4 + lane) * NWAVE + gw, pack_tag(yR, 1u));
        tag_store(Rtag + (size_t)(4 + lane) * NWAVE + gw,     pack_tag(Ra, 1u));
        // out[0] = initial state (plain stores, off critical path)
        out[0 * NN + i] = yI;
        out[1 * NN + i] = yH;
        out[2 * NN + i] = yA;
        out[3 * NN + i] = yR;
    }

    for (int p = 0; p < NP; ++p) {
        const int n = p >> 1;
        const unsigned tgt = (unsigned)p + 1u;
        u64* T0 = Rtag + (size_t)((p & 1) * 8 + 0) * NWAVE;  // vec0 planes j=0..3
        u64* T1 = Rtag + (size_t)((p & 1) * 8 + 4) * NWAVE;  // vec1 planes j=0..3

        float a0 = 0.f, a1 = 0.f, a2 = 0.f, a3 = 0.f;
        float b0 = 0.f, b1 = 0.f, b2 = 0.f, b3 = 0.f;

#pragma unroll
        for (int k = 0; k < 8; ++k) {
            const int widx = 64 * k + lane;   // producer wave for this lane
            u64 t0, t1, t2, t3, s0, s1, s2, s3;
            for (;;) {
                t0 = tag_load(T0 + 0 * NWAVE + widx);
                t1 = tag_load(T0 + 1 * NWAVE + widx);
                t2 = tag_load(T0 + 2 * NWAVE + widx);
                t3 = tag_load(T0 + 3 * NWAVE + widx);
                s0 = tag_load(T1 + 0 * NWAVE + widx);
                s1 = tag_load(T1 + 1 * NWAVE + widx);
                s2 = tag_load(T1 + 2 * NWAVE + widx);
                s3 = tag_load(T1 + 3 * NWAVE + widx);
                const bool ok = ((unsigned)(t0 >> 32) == tgt) &
                                ((unsigned)(t1 >> 32) == tgt) &
                                ((unsigned)(t2 >> 32) == tgt) &
                                ((unsigned)(t3 >> 32) == tgt) &
                                ((unsigned)(s0 >> 32) == tgt) &
                                ((unsigned)(s1 >> 32) == tgt) &
                                ((unsigned)(s2 >> 32) == tgt) &
                                ((unsigned)(s3 >> 32) == tgt);
                if (ok) break;
                __builtin_amdgcn_s_sleep(1);
            }
            const f4 ra = { __uint_as_float((unsigned)t0),
                            __uint_as_float((unsigned)t1),
                            __uint_as_float((unsigned)t2),
                            __uint_as_float((unsigned)t3) };
            const f4 rb = { __uint_as_float((unsigned)s0),
                            __uint_as_float((unsigned)s1),
                            __uint_as_float((unsigned)s2),
                            __uint_as_float((unsigned)s3) };
            a0 += dot4(w[0][k], ra);
            a1 += dot4(w[1][k], ra);
            a2 += dot4(w[2][k], ra);
            a3 += dot4(w[3][k], ra);
            b0 += dot4(w[0][k], rb);
            b1 += dot4(w[1][k], rb);
            b2 += dot4(w[2][k], rb);
            b3 += dot4(w[3][k], rb);
        }

#pragma unroll
        for (int off = 32; off > 0; off >>= 1) {
            a0 += __shfl_xor(a0, off, 64);
            a1 += __shfl_xor(a1, off, 64);
            a2 += __shfl_xor(a2, off, 64);
            a3 += __shfl_xor(a3, off, 64);
            b0 += __shfl_xor(b0, off, 64);
            b1 += __shfl_xor(b1, off, 64);
            b2 += __shfl_xor(b2, off, 64);
            b3 += __shfl_xor(b3, off, 64);
        }

        // ---- owner update: lane r (<4) uses row sums (a_r, b_r) ----
        bool wrote_out = false;
        float oI = 0.f, oH = 0.f, oA = 0.f, oR = 0.f;
        if (lane < 4) {
            const int   r  = lane;
            const float u1 = (r == 0) ? a0 : (r == 1) ? a1 : (r == 2) ? a2 : a3;
            const float u2 = (r == 0) ? b0 : (r == 1) ? b1 : (r == 2) ? b2 : b3;
            const float dt = tg[n + 1] - tg[n];
            const unsigned seq = (unsigned)p + 2u;
            u64* P0 = Rtag + (size_t)(((p + 1) & 1) * 8 + r) * NWAVE + gw;
            u64* P1 = P0 + 4 * NWAVE;
            float v0, v1;

            if ((p & 1) == 0) {
                // phase A: k1, k2, y_b; publish R_b, R_c
                k1I = -yI / 5.0f + u1 + 0.1f + st;
                k1H = (-yH + 1.5f * k1I) / 10.0f;
                k1A = (-yA + 0.2f * yR) / 20.0f;
                k1R = tanhf(yH - yA);
                const float h = 0.5f * dt;
                const float aI_ = yI + h * k1I, aH_ = yH + h * k1H;
                const float aA_ = yA + h * k1A, aR_ = yR + h * k1R;
                k2I = -aI_ / 5.0f + u2 + 0.1f + st;
                k2H = (-aH_ + 1.5f * k2I) / 10.0f;
                k2A = (-aA_ + 0.2f * aR_) / 20.0f;
                k2R = tanhf(aH_ - aA_);
                bI = yI + h * k2I;  bH = yH + h * k2H;
                bA = yA + h * k2A;  bR = yR + h * k2R;
                const float k3R = tanhf(bH - bA);
                v0 = bR;              // R_b
                v1 = yR + dt * k3R;   // R_c
            } else {
                // phase B: k3, k4, combine; publish R_{n+1}, R_a'
                const float k3I = -bI / 5.0f + u1 + 0.1f + st;
                const float k3H = (-bH + 1.5f * k3I) / 10.0f;
                const float k3A = (-bA + 0.2f * bR) / 20.0f;
                const float k3R = tanhf(bH - bA);
                const float cI = yI + dt * k3I, cH = yH + dt * k3H;
                const float cA = yA + dt * k3A, cR = yR + dt * k3R;
                const float k4I = -cI / 5.0f + u2 + 0.1f + st;
                const float k4H = (-cH + 1.5f * k4I) / 10.0f;
                const float k4A = (-cA + 0.2f * cR) / 20.0f;
                const float k4R = tanhf(cH - cA);
                const float h6 = dt / 6.0f;
                yI = yI + h6 * ((k1I + 2.0f * k2I) + 2.0f * k3I + k4I);
                yH = yH + h6 * ((k1H + 2.0f * k2H) + 2.0f * k3H + k4H);
                yA = yA + h6 * ((k1A + 2.0f * k2A) + 2.0f * k3A + k4A);
                yR = yR + h6 * ((k1R + 2.0f * k2R) + 2.0f * k3R + k4R);
                const float dtn = (n + 2 < TT) ? (tg[n + 2] - tg[n + 1]) : 0.0f;
                v0 = yR;                                   // R_{n+1}
                v1 = yR + (0.5f * dtn) * tanhf(yH - yA);   // R_a'
                oI = yI; oH = yH; oA = yA; oR = yR;
                wrote_out = true;
            }
            // fire-and-forget tagged publishes (atomic 8B: tag+value together)
            tag_store(P0, pack_tag(v0, seq));
            tag_store(P1, pack_tag(v1, seq));
        }
        // trajectory store off the critical path (overlaps next phase's polls)
        if (wrote_out) {
            const int i = myrow + lane;
            float* o = out + (size_t)(n + 1) * 4 * NN;
            o[0 * NN + i] = oI;
            o[1 * NN + i] = oH;
            o[2 * NN + i] = oA;
            o[3 * NN + i] = oR;
        }
    }
}

extern "C" void kernel_launch(void* const* d_in, const int* in_sizes, int n_in,
                              void* d_out, int out_size, void* d_ws, size_t ws_size,
                              hipStream_t stream)
{
    const float* tgrid  = (const float*)d_in[0];
    const float* state0 = (const float*)d_in[1];
    const float* stim   = (const float*)d_in[2];
    const float* W      = (const float*)d_in[3];
    float*       out    = (float*)d_out;
    u64*         Rtag   = (u64*)d_ws;   // 2*2*4*512 u64 = 64KB

    // Zero ALL tags every launch (poison/stale tags must never alias a live
    // tag; 0 matches no tgt >= 1). Stream-ordered before the kernel.
    hipMemsetAsync(Rtag, 0, 2 * 2 * 4 * NWAVE * sizeof(u64), stream);

    // LDS pad: actual use 8KB; pad so 2 WGs can't share a CU (one WG per CU,
    // each producer wave gets a SIMD to itself).
    const size_t dyn_lds = 84 * 1024;
    (void)hipFuncSetAttribute((const void*)node_rk4_kernel,
                              hipFuncAttributeMaxDynamicSharedMemorySize,
                              (int)dyn_lds);   // unconditional: same work every call

    node_rk4_kernel<<<dim3(NWG), dim3(TPB), dyn_lds, stream>>>(
        tgrid, state0, stim, W, out, Rtag);
}